// Round 9
// baseline (123.210 us; speedup 1.0000x reference)
//
#include <hip/hip_runtime.h>

#define SB 32      // batch
#define SS 2048    // sequence
#define SH 2       // heads
#define SD 4       // head dim
#define SE 8       // embed

#define KCHUNKS 8
#define CHK (SS / KCHUNKS)    // 256 keys per chunk
#define QTILES 2
#define QROWS (SS / QTILES)   // 1024 q rows per block = 256 threads * RROWS
#define RROWS 4               // q rows per thread (ILP streams)

#define LOG2E 1.44269504f

typedef float f32x2 __attribute__((ext_vector_type(2)));
static __device__ __forceinline__ f32x2 fma2(f32x2 a, f32x2 b, f32x2 c) {
    return __builtin_elementwise_fma(a, b, c);
}

// ---------------------------------------------------------------------------
// Kernel 1: moving averages + QKV projection (q pre-scaled by log2e/sqrt(D)),
// K/V stored interleaved (one 32B record per key), and per-(b,h) global max
// of |q|^2 / |k|^2 via LDS reduce + atomicMax (values >= 0 so int-compare
// atomicMax is order-preserving).
// ---------------------------------------------------------------------------
__global__ __launch_bounds__(256) void k_ma_qkv(
    const float* __restrict__ x,      // [B,S]
    const float* __restrict__ Wq,     // [4,4] row-major W[e*4+d]
    const float* __restrict__ Wk,
    const float* __restrict__ Wv,
    float4* __restrict__ qws,         // [B*H*S]
    float4* __restrict__ kvws,        // [B*H*S*2] interleaved K,V
    float4* __restrict__ mmws,        // [B*S*2]
    float* __restrict__ Mq2,          // [B*H] (zero-initialized)
    float* __restrict__ Mk2)          // [B*H]
{
    __shared__ float xs[272];
    __shared__ float4 red4[256];

    const int tile = blockIdx.x % (SS / 256);
    const int b    = blockIdx.x / (SS / 256);
    const int s0   = tile * 256;
    const float* xrow = x + b * SS;

    for (int i = threadIdx.x; i < 272; i += 256) {
        int idx = s0 - 8 + i;
        idx = min(max(idx, 0), SS - 1);
        xs[i] = xrow[idx];
    }
    __syncthreads();

    const int t = threadIdx.x;
    const int s = s0 + t;

    float mmv[8];
    float c = xs[8 + t];
    #pragma unroll
    for (int h = 1; h <= 8; ++h) {
        c += xs[8 + t - h] + xs[8 + t + h];
        mmv[h - 1] = c * (1.0f / (float)(2 * h + 1));
    }

    mmws[(b * SS + s) * 2 + 0] = make_float4(mmv[0], mmv[1], mmv[2], mmv[3]);
    mmws[(b * SS + s) * 2 + 1] = make_float4(mmv[4], mmv[5], mmv[6], mmv[7]);

    const float qscale = 0.5f * LOG2E;  // 1/sqrt(D) * log2(e)
    float q2h[SH], k2h[SH];
    #pragma unroll
    for (int h = 0; h < SH; ++h) {
        const float t0 = mmv[h * 4 + 0];
        const float t1 = mmv[h * 4 + 1];
        const float t2 = mmv[h * 4 + 2];
        const float t3 = mmv[h * 4 + 3];
        float q[4], k[4], v[4];
        #pragma unroll
        for (int e = 0; e < 4; ++e) {
            q[e] = (t0 * Wq[e * 4 + 0] + t1 * Wq[e * 4 + 1] +
                    t2 * Wq[e * 4 + 2] + t3 * Wq[e * 4 + 3]) * qscale;
            k[e] =  t0 * Wk[e * 4 + 0] + t1 * Wk[e * 4 + 1] +
                    t2 * Wk[e * 4 + 2] + t3 * Wk[e * 4 + 3];
            v[e] =  t0 * Wv[e * 4 + 0] + t1 * Wv[e * 4 + 1] +
                    t2 * Wv[e * 4 + 2] + t3 * Wv[e * 4 + 3];
        }
        const int idx = (b * SH + h) * SS + s;
        qws[idx]          = make_float4(q[0], q[1], q[2], q[3]);
        kvws[idx * 2 + 0] = make_float4(k[0], k[1], k[2], k[3]);
        kvws[idx * 2 + 1] = make_float4(v[0], v[1], v[2], v[3]);
        q2h[h] = q[0]*q[0] + q[1]*q[1] + q[2]*q[2] + q[3]*q[3];
        k2h[h] = k[0]*k[0] + k[1]*k[1] + k[2]*k[2] + k[3]*k[3];
    }

    red4[t] = make_float4(q2h[0], k2h[0], q2h[1], k2h[1]);
    __syncthreads();
    #pragma unroll
    for (int sft = 128; sft > 0; sft >>= 1) {
        if (t < sft) {
            float4 a = red4[t], bb = red4[t + sft];
            red4[t] = make_float4(fmaxf(a.x, bb.x), fmaxf(a.y, bb.y),
                                  fmaxf(a.z, bb.z), fmaxf(a.w, bb.w));
        }
        __syncthreads();
    }
    if (t == 0) {
        const float4 r = red4[0];
        atomicMax((int*)&Mq2[b * SH + 0], __float_as_int(r.x));
        atomicMax((int*)&Mk2[b * SH + 0], __float_as_int(r.y));
        atomicMax((int*)&Mq2[b * SH + 1], __float_as_int(r.z));
        atomicMax((int*)&Mk2[b * SH + 1], __float_as_int(r.w));
    }
}

// ---------------------------------------------------------------------------
// Kernel 2: attention, single pass, RROWS=4 independent dot->exp->accum
// streams per thread (ILP hides v_exp / LDS latency). 256 threads * 4 rows
// = 1024 rows = QROWS per block (geometry consistent — R8 bug was
// QROWS=512 with 1024 rows touched). K/V chunk (8 KB) in LDS; j-loop
// address wave-uniform -> broadcast. Shift bound m = sqrt(Mq2*Mk2) per
// (b,h) seeds the dot; base-2 throughout.
// Grid = B*H * QTILES * KCHUNKS = 1024 blocks -> 4 blocks/CU, 16 waves/CU.
// ---------------------------------------------------------------------------
__global__ __launch_bounds__(256, 4) void k_attn(
    const float4* __restrict__ qws,
    const float4* __restrict__ kvws,
    const float* __restrict__ Mq2,
    const float* __restrict__ Mk2,
    float* __restrict__ pl,      // [KCHUNKS * B*H*S]  partial sums l
    float4* __restrict__ pacc)   // [KCHUNKS * B*H*S]
{
    __shared__ float4 KVsh[2 * CHK];   // 8 KB interleaved {K,V} records

    int tmp = blockIdx.x;
    const int kc = tmp % KCHUNKS; tmp /= KCHUNKS;
    const int qt = tmp % QTILES;  tmp /= QTILES;
    const int bh = tmp;

    const int t = threadIdx.x;

    const float4* __restrict__ KVg = kvws + (bh * SS + kc * CHK) * 2;
    // stage: 2 float4 per thread (2*CHK = 512 records of 16B)
    #pragma unroll
    for (int i = 0; i < 2 * CHK / 256; ++i)
        KVsh[i * 256 + t] = KVg[i * 256 + t];

    const float mq = -sqrtf(Mq2[bh] * Mk2[bh]);   // -m, log2 units

    f32x2 qlo[RROWS], qhi[RROWS];
    int row[RROWS];
    #pragma unroll
    for (int i = 0; i < RROWS; ++i) {
        row[i] = qt * QROWS + i * 256 + t;   // 4*256 = 1024 = QROWS
        const float4 q = qws[bh * SS + row[i]];
        qlo[i] = f32x2{q.x, q.y};
        qhi[i] = f32x2{q.z, q.w};
    }

    float l[RROWS] = {0.f, 0.f, 0.f, 0.f};
    f32x2 acclo[RROWS], acchi[RROWS];
    #pragma unroll
    for (int i = 0; i < RROWS; ++i) {
        acclo[i] = f32x2{0.f, 0.f};
        acchi[i] = f32x2{0.f, 0.f};
    }

    __syncthreads();

    #pragma unroll 4
    for (int j = 0; j < CHK; ++j) {
        const float4 k4 = KVsh[2 * j];       // uniform addr -> broadcast
        const float4 v4 = KVsh[2 * j + 1];
        const f32x2 klo = {k4.x, k4.y}, khi = {k4.z, k4.w};
        const f32x2 vlo = {v4.x, v4.y}, vhi = {v4.z, v4.w};
        #pragma unroll
        for (int i = 0; i < RROWS; ++i) {
            f32x2 d = fma2(qlo[i], klo, f32x2{mq, 0.f});
            d = fma2(qhi[i], khi, d);
            const float p = exp2f(d.x + d.y);   // arg = q.k - m
            l[i] += p;
            const f32x2 pp = {p, p};
            acclo[i] = fma2(pp, vlo, acclo[i]);
            acchi[i] = fma2(pp, vhi, acchi[i]);
        }
    }

    #pragma unroll
    for (int i = 0; i < RROWS; ++i) {
        const int idx = (kc * SB * SH + bh) * SS + row[i];
        pl[idx]   = l[i];
        pacc[idx] = make_float4(acclo[i].x, acclo[i].y, acchi[i].x, acchi[i].y);
    }
}

// ---------------------------------------------------------------------------
// Kernel 3: epilogue. Shift m identical across k-chunks -> plain-sum merge.
// Then o @ Wo^T + bo, channel softmax, trend, seasonal.
// ---------------------------------------------------------------------------
__global__ __launch_bounds__(256) void k_epilogue(
    const float* __restrict__ x,      // [B,S]
    const float* __restrict__ Wo,     // [8,8]
    const float* __restrict__ bo,     // [8]
    const float* __restrict__ pl,
    const float4* __restrict__ pacc,
    const float4* __restrict__ mmws,
    float* __restrict__ out)          // seasonal [B*S] then trend [B*S]
{
    const int pos = blockIdx.x * 256 + threadIdx.x;  // = b*S + s
    const int b = pos / SS;
    const int s = pos % SS;

    float ov[8];
    #pragma unroll
    for (int h = 0; h < SH; ++h) {
        const int bh = b * SH + h;
        float lsum = 0.f, ax = 0.f, ay = 0.f, az = 0.f, aw = 0.f;
        #pragma unroll
        for (int kc = 0; kc < KCHUNKS; ++kc) {
            const int idx = (kc * SB * SH + bh) * SS + s;
            const float4 pa = pacc[idx];
            lsum += pl[idx];
            ax += pa.x; ay += pa.y; az += pa.z; aw += pa.w;
        }
        const float inv = 1.0f / lsum;
        ov[h * 4 + 0] = ax * inv;
        ov[h * 4 + 1] = ay * inv;
        ov[h * 4 + 2] = az * inv;
        ov[h * 4 + 3] = aw * inv;
    }

    float g[8];
    float m = -1e30f;
    #pragma unroll
    for (int e = 0; e < 8; ++e) {
        float acc = bo[e];
        #pragma unroll
        for (int f = 0; f < 8; ++f) acc += ov[f] * Wo[e * 8 + f];
        g[e] = acc;
        m = fmaxf(m, acc);
    }
    float l = 0.0f;
    #pragma unroll
    for (int e = 0; e < 8; ++e) { g[e] = __expf(g[e] - m); l += g[e]; }
    const float inv = 1.0f / l;

    const float4 mm0 = mmws[pos * 2 + 0];
    const float4 mm1 = mmws[pos * 2 + 1];
    const float mv[8] = {mm0.x, mm0.y, mm0.z, mm0.w, mm1.x, mm1.y, mm1.z, mm1.w};

    float trend = 0.0f;
    #pragma unroll
    for (int e = 0; e < 8; ++e) trend += g[e] * inv * mv[e];

    out[pos]           = x[pos] - trend;   // seasonal
    out[SB * SS + pos] = trend;            // trend
}

extern "C" void kernel_launch(void* const* d_in, const int* in_sizes, int n_in,
                              void* d_out, int out_size, void* d_ws, size_t ws_size,
                              hipStream_t stream) {
    const float* x  = (const float*)d_in[0];
    const float* Wq = (const float*)d_in[1];
    const float* Wk = (const float*)d_in[2];
    const float* Wv = (const float*)d_in[3];
    const float* Wo = (const float*)d_in[4];
    const float* bo = (const float*)d_in[5];

    float*  Mq2  = (float*)d_ws;                              // 64 floats
    float*  Mk2  = Mq2 + SB * SH;                             // 64 floats (512 B total)
    float4* qws  = (float4*)((char*)d_ws + 512);              // 2 MB
    float4* kvws = qws + SB * SH * SS;                        // 4 MB (interleaved K,V)
    float4* mmws = kvws + 2 * SB * SH * SS;                   // 2 MB
    float4* pacc = mmws + SB * SS * 2;                        // 16 MB
    float*  pl   = (float*)(pacc + KCHUNKS * SB * SH * SS);   // 4 MB

    hipMemsetAsync(d_ws, 0, 512, stream);  // zero Mq2/Mk2 (values >= 0)

    k_ma_qkv<<<SB * (SS / 256), 256, 0, stream>>>(x, Wq, Wk, Wv, qws, kvws, mmws, Mq2, Mk2);
    k_attn<<<SB * SH * QTILES * KCHUNKS, 256, 0, stream>>>(qws, kvws, Mq2, Mk2, pl, pacc);
    k_epilogue<<<(SB * SS) / 256, 256, 0, stream>>>(x, Wo, bo, pl, pacc, mmws, (float*)d_out);
}

// Round 10
// 91.537 us; speedup vs baseline: 1.3460x; 1.3460x over previous
//
#include <hip/hip_runtime.h>

#define SB 32      // batch
#define SS 2048    // sequence
#define SH 2       // heads
#define SD 4       // head dim
#define SE 8       // embed

#define KCHUNKS 8
#define CHK (SS / KCHUNKS)    // 256 keys per chunk
#define QTILES 2
#define QROWS (SS / QTILES)   // 1024 q rows per block = 256 threads * RROWS
#define RROWS 4               // q rows per thread (ILP streams)

#define LOG2E 1.44269504f

typedef float f32x2 __attribute__((ext_vector_type(2)));
static __device__ __forceinline__ f32x2 fma2(f32x2 a, f32x2 b, f32x2 c) {
    return __builtin_elementwise_fma(a, b, c);
}

// Raw v_exp_f32 (1 trans instr). Without -ffast-math, libm exp2f lowers to
// the OCML denormal-safe path (~5 instr: cmp/cndmask/exp/cndmask). Our args
// are in [-100, 0] so the fixup path is dead weight.
static __device__ __forceinline__ float fast_exp2(float x) {
#if __has_builtin(__builtin_amdgcn_exp2f)
    return __builtin_amdgcn_exp2f(x);
#else
    return exp2f(x);
#endif
}

// ---------------------------------------------------------------------------
// Kernel 1: moving averages + QKV projection (q pre-scaled by log2e/sqrt(D)),
// K/V stored interleaved (one 32B record per key), and per-(b,h) global max
// of |q|^2 / |k|^2 via LDS reduce + atomicMax (values >= 0 so int-compare
// atomicMax is order-preserving).
// ---------------------------------------------------------------------------
__global__ __launch_bounds__(256) void k_ma_qkv(
    const float* __restrict__ x,      // [B,S]
    const float* __restrict__ Wq,     // [4,4] row-major W[e*4+d]
    const float* __restrict__ Wk,
    const float* __restrict__ Wv,
    float4* __restrict__ qws,         // [B*H*S]
    float4* __restrict__ kvws,        // [B*H*S*2] interleaved K,V
    float4* __restrict__ mmws,        // [B*S*2]
    float* __restrict__ Mq2,          // [B*H] (zero-initialized)
    float* __restrict__ Mk2)          // [B*H]
{
    __shared__ float xs[272];
    __shared__ float4 red4[256];

    const int tile = blockIdx.x % (SS / 256);
    const int b    = blockIdx.x / (SS / 256);
    const int s0   = tile * 256;
    const float* xrow = x + b * SS;

    for (int i = threadIdx.x; i < 272; i += 256) {
        int idx = s0 - 8 + i;
        idx = min(max(idx, 0), SS - 1);
        xs[i] = xrow[idx];
    }
    __syncthreads();

    const int t = threadIdx.x;
    const int s = s0 + t;

    float mmv[8];
    float c = xs[8 + t];
    #pragma unroll
    for (int h = 1; h <= 8; ++h) {
        c += xs[8 + t - h] + xs[8 + t + h];
        mmv[h - 1] = c * (1.0f / (float)(2 * h + 1));
    }

    mmws[(b * SS + s) * 2 + 0] = make_float4(mmv[0], mmv[1], mmv[2], mmv[3]);
    mmws[(b * SS + s) * 2 + 1] = make_float4(mmv[4], mmv[5], mmv[6], mmv[7]);

    const float qscale = 0.5f * LOG2E;  // 1/sqrt(D) * log2(e)
    float q2h[SH], k2h[SH];
    #pragma unroll
    for (int h = 0; h < SH; ++h) {
        const float t0 = mmv[h * 4 + 0];
        const float t1 = mmv[h * 4 + 1];
        const float t2 = mmv[h * 4 + 2];
        const float t3 = mmv[h * 4 + 3];
        float q[4], k[4], v[4];
        #pragma unroll
        for (int e = 0; e < 4; ++e) {
            q[e] = (t0 * Wq[e * 4 + 0] + t1 * Wq[e * 4 + 1] +
                    t2 * Wq[e * 4 + 2] + t3 * Wq[e * 4 + 3]) * qscale;
            k[e] =  t0 * Wk[e * 4 + 0] + t1 * Wk[e * 4 + 1] +
                    t2 * Wk[e * 4 + 2] + t3 * Wk[e * 4 + 3];
            v[e] =  t0 * Wv[e * 4 + 0] + t1 * Wv[e * 4 + 1] +
                    t2 * Wv[e * 4 + 2] + t3 * Wv[e * 4 + 3];
        }
        const int idx = (b * SH + h) * SS + s;
        qws[idx]          = make_float4(q[0], q[1], q[2], q[3]);
        kvws[idx * 2 + 0] = make_float4(k[0], k[1], k[2], k[3]);
        kvws[idx * 2 + 1] = make_float4(v[0], v[1], v[2], v[3]);
        q2h[h] = q[0]*q[0] + q[1]*q[1] + q[2]*q[2] + q[3]*q[3];
        k2h[h] = k[0]*k[0] + k[1]*k[1] + k[2]*k[2] + k[3]*k[3];
    }

    red4[t] = make_float4(q2h[0], k2h[0], q2h[1], k2h[1]);
    __syncthreads();
    #pragma unroll
    for (int sft = 128; sft > 0; sft >>= 1) {
        if (t < sft) {
            float4 a = red4[t], bb = red4[t + sft];
            red4[t] = make_float4(fmaxf(a.x, bb.x), fmaxf(a.y, bb.y),
                                  fmaxf(a.z, bb.z), fmaxf(a.w, bb.w));
        }
        __syncthreads();
    }
    if (t == 0) {
        const float4 r = red4[0];
        atomicMax((int*)&Mq2[b * SH + 0], __float_as_int(r.x));
        atomicMax((int*)&Mk2[b * SH + 0], __float_as_int(r.y));
        atomicMax((int*)&Mq2[b * SH + 1], __float_as_int(r.z));
        atomicMax((int*)&Mk2[b * SH + 1], __float_as_int(r.w));
    }
}

// ---------------------------------------------------------------------------
// Kernel 2: attention, single pass, RROWS=4 streams/thread, K/V chunk (8 KB)
// in LDS (wave-uniform j -> broadcast ds_read_b128). Shift bound
// m = sqrt(Mq2*Mk2) per (b,h) seeds the dot; base-2 throughout; raw
// v_exp_f32 via fast_exp2.
// Grid = B*H * QTILES * KCHUNKS = 1024 blocks -> 4 blocks/CU, 16 waves/CU.
// ---------------------------------------------------------------------------
__global__ __launch_bounds__(256, 4) void k_attn(
    const float4* __restrict__ qws,
    const float4* __restrict__ kvws,
    const float* __restrict__ Mq2,
    const float* __restrict__ Mk2,
    float* __restrict__ pl,      // [KCHUNKS * B*H*S]  partial sums l
    float4* __restrict__ pacc)   // [KCHUNKS * B*H*S]
{
    __shared__ float4 KVsh[2 * CHK];   // 8 KB interleaved {K,V} records

    int tmp = blockIdx.x;
    const int kc = tmp % KCHUNKS; tmp /= KCHUNKS;
    const int qt = tmp % QTILES;  tmp /= QTILES;
    const int bh = tmp;

    const int t = threadIdx.x;

    const float4* __restrict__ KVg = kvws + (bh * SS + kc * CHK) * 2;
    #pragma unroll
    for (int i = 0; i < 2 * CHK / 256; ++i)
        KVsh[i * 256 + t] = KVg[i * 256 + t];

    const float mq = -sqrtf(Mq2[bh] * Mk2[bh]);   // -m, log2 units

    f32x2 qlo[RROWS], qhi[RROWS];
    int row[RROWS];
    #pragma unroll
    for (int i = 0; i < RROWS; ++i) {
        row[i] = qt * QROWS + i * 256 + t;   // 4*256 = 1024 = QROWS
        const float4 q = qws[bh * SS + row[i]];
        qlo[i] = f32x2{q.x, q.y};
        qhi[i] = f32x2{q.z, q.w};
    }

    float l[RROWS] = {0.f, 0.f, 0.f, 0.f};
    f32x2 acclo[RROWS], acchi[RROWS];
    #pragma unroll
    for (int i = 0; i < RROWS; ++i) {
        acclo[i] = f32x2{0.f, 0.f};
        acchi[i] = f32x2{0.f, 0.f};
    }

    __syncthreads();

    #pragma unroll 4
    for (int j = 0; j < CHK; ++j) {
        const float4 k4 = KVsh[2 * j];       // uniform addr -> broadcast
        const float4 v4 = KVsh[2 * j + 1];
        const f32x2 klo = {k4.x, k4.y}, khi = {k4.z, k4.w};
        const f32x2 vlo = {v4.x, v4.y}, vhi = {v4.z, v4.w};
        #pragma unroll
        for (int i = 0; i < RROWS; ++i) {
            f32x2 d = fma2(qlo[i], klo, f32x2{mq, 0.f});
            d = fma2(qhi[i], khi, d);
            const float p = fast_exp2(d.x + d.y);   // arg = q.k - m, in [-100,0]
            l[i] += p;
            const f32x2 pp = {p, p};
            acclo[i] = fma2(pp, vlo, acclo[i]);
            acchi[i] = fma2(pp, vhi, acchi[i]);
        }
    }

    #pragma unroll
    for (int i = 0; i < RROWS; ++i) {
        const int idx = (kc * SB * SH + bh) * SS + row[i];
        pl[idx]   = l[i];
        pacc[idx] = make_float4(acclo[i].x, acclo[i].y, acchi[i].x, acchi[i].y);
    }
}

// ---------------------------------------------------------------------------
// Kernel 3: epilogue. Shift m identical across k-chunks -> plain-sum merge.
// Then o @ Wo^T + bo, channel softmax, trend, seasonal.
// ---------------------------------------------------------------------------
__global__ __launch_bounds__(256) void k_epilogue(
    const float* __restrict__ x,      // [B,S]
    const float* __restrict__ Wo,     // [8,8]
    const float* __restrict__ bo,     // [8]
    const float* __restrict__ pl,
    const float4* __restrict__ pacc,
    const float4* __restrict__ mmws,
    float* __restrict__ out)          // seasonal [B*S] then trend [B*S]
{
    const int pos = blockIdx.x * 256 + threadIdx.x;  // = b*S + s
    const int b = pos / SS;
    const int s = pos % SS;

    float ov[8];
    #pragma unroll
    for (int h = 0; h < SH; ++h) {
        const int bh = b * SH + h;
        float lsum = 0.f, ax = 0.f, ay = 0.f, az = 0.f, aw = 0.f;
        #pragma unroll
        for (int kc = 0; kc < KCHUNKS; ++kc) {
            const int idx = (kc * SB * SH + bh) * SS + s;
            const float4 pa = pacc[idx];
            lsum += pl[idx];
            ax += pa.x; ay += pa.y; az += pa.z; aw += pa.w;
        }
        const float inv = 1.0f / lsum;
        ov[h * 4 + 0] = ax * inv;
        ov[h * 4 + 1] = ay * inv;
        ov[h * 4 + 2] = az * inv;
        ov[h * 4 + 3] = aw * inv;
    }

    float g[8];
    float m = -1e30f;
    #pragma unroll
    for (int e = 0; e < 8; ++e) {
        float acc = bo[e];
        #pragma unroll
        for (int f = 0; f < 8; ++f) acc += ov[f] * Wo[e * 8 + f];
        g[e] = acc;
        m = fmaxf(m, acc);
    }
    float l = 0.0f;
    #pragma unroll
    for (int e = 0; e < 8; ++e) { g[e] = __expf(g[e] - m); l += g[e]; }
    const float inv = 1.0f / l;

    const float4 mm0 = mmws[pos * 2 + 0];
    const float4 mm1 = mmws[pos * 2 + 1];
    const float mv[8] = {mm0.x, mm0.y, mm0.z, mm0.w, mm1.x, mm1.y, mm1.z, mm1.w};

    float trend = 0.0f;
    #pragma unroll
    for (int e = 0; e < 8; ++e) trend += g[e] * inv * mv[e];

    out[pos]           = x[pos] - trend;   // seasonal
    out[SB * SS + pos] = trend;            // trend
}

extern "C" void kernel_launch(void* const* d_in, const int* in_sizes, int n_in,
                              void* d_out, int out_size, void* d_ws, size_t ws_size,
                              hipStream_t stream) {
    const float* x  = (const float*)d_in[0];
    const float* Wq = (const float*)d_in[1];
    const float* Wk = (const float*)d_in[2];
    const float* Wv = (const float*)d_in[3];
    const float* Wo = (const float*)d_in[4];
    const float* bo = (const float*)d_in[5];

    float*  Mq2  = (float*)d_ws;                              // 64 floats
    float*  Mk2  = Mq2 + SB * SH;                             // 64 floats (512 B total)
    float4* qws  = (float4*)((char*)d_ws + 512);              // 2 MB
    float4* kvws = qws + SB * SH * SS;                        // 4 MB (interleaved K,V)
    float4* mmws = kvws + 2 * SB * SH * SS;                   // 2 MB
    float4* pacc = mmws + SB * SS * 2;                        // 16 MB
    float*  pl   = (float*)(pacc + KCHUNKS * SB * SH * SS);   // 4 MB

    hipMemsetAsync(d_ws, 0, 512, stream);  // zero Mq2/Mk2 (values >= 0)

    k_ma_qkv<<<SB * (SS / 256), 256, 0, stream>>>(x, Wq, Wk, Wv, qws, kvws, mmws, Mq2, Mk2);
    k_attn<<<SB * SH * QTILES * KCHUNKS, 256, 0, stream>>>(qws, kvws, Mq2, Mk2, pl, pacc);
    k_epilogue<<<(SB * SS) / 256, 256, 0, stream>>>(x, Wo, bo, pl, pacc, mmws, (float*)d_out);
}